// Round 13
// baseline (1393.120 us; speedup 1.0000x reference)
//
#include <hip/hip_runtime.h>
#include <cstdint>

typedef float f32x4 __attribute__((ext_vector_type(4)));
typedef __bf16 bf16x8 __attribute__((ext_vector_type(8)));
typedef unsigned short ushort4v __attribute__((ext_vector_type(4)));
typedef unsigned short u16;
typedef unsigned int u32;

// ---------- helpers ----------
__device__ __forceinline__ u16 f2bf(float f) {
  u32 u = __builtin_bit_cast(u32, f);
  u32 r = (u + 0x7fffu + ((u >> 16) & 1u)) >> 16;
  return (u16)r;
}

__device__ __forceinline__ float4 b2f4(ushort4v v) {
  float4 o;
  o.x = __builtin_bit_cast(float, (u32)v[0] << 16);
  o.y = __builtin_bit_cast(float, (u32)v[1] << 16);
  o.z = __builtin_bit_cast(float, (u32)v[2] << 16);
  o.w = __builtin_bit_cast(float, (u32)v[3] << 16);
  return o;
}

__device__ __forceinline__ void gload_lds16(const void* g, void* lds) {
  __builtin_amdgcn_global_load_lds(
      (const __attribute__((address_space(1))) u32*)g,
      (__attribute__((address_space(3))) u32*)lds,
      16, 0, 0);
}

// ---------- one-time: cast + transpose weights to bf16 ----------
__global__ __launch_bounds__(256) void k_cast_weights(
    const float* __restrict__ W1, const float* __restrict__ W2,
    u16* __restrict__ w1t, u16* __restrict__ w2t) {
  const int PER = 5 * 512 * 256;
  int idx = blockIdx.x * 256 + threadIdx.x;
  if (idx < PER) {
    int l = idx / (512 * 256);
    int rem = idx % (512 * 256);
    int n = rem / 256, k = rem % 256;
    w1t[idx] = f2bf(W1[l * 131072 + k * 512 + n]);
  } else if (idx < 2 * PER) {
    int j = idx - PER;
    int l = j / (256 * 512);
    int rem = j % (256 * 512);
    int n = rem / 512, k = rem % 512;
    w2t[j] = f2bf(W2[l * 131072 + k * 256 + n]);
  }
}

// ---------- node input embedding (bf16 h0) ----------
__global__ __launch_bounds__(256) void k_node_init(
    const int* __restrict__ xa, const int* __restrict__ xc,
    const float* __restrict__ e1, const float* __restrict__ e2,
    u16* __restrict__ h, int N) {
  int idx = blockIdx.x * 256 + threadIdx.x;
  if (idx >= N * 64) return;
  int node = idx >> 6, c = (idx & 63) * 4;
  int a = xa[node], ch = xc[node];
  float4 v1 = *(const float4*)&e1[a * 256 + c];
  float4 v2 = *(const float4*)&e2[ch * 256 + c];
  ushort4v o;
  o[0] = f2bf(v1.x + v2.x); o[1] = f2bf(v1.y + v2.y);
  o[2] = f2bf(v1.z + v2.z); o[3] = f2bf(v1.w + v2.w);
  *(ushort4v*)&h[(size_t)node * 256 + c] = o;
}

// ---------- CSR build ----------
__global__ __launch_bounds__(256) void k_deg_count(
    const int* __restrict__ dst, int* __restrict__ deg, int E) {
  int e = blockIdx.x * 256 + threadIdx.x;
  if (e < E) atomicAdd(&deg[dst[e]], 1);
}

__global__ __launch_bounds__(256) void k_scan1(
    const int* __restrict__ deg, int* __restrict__ rp,
    int* __restrict__ bsum, int N) {
  __shared__ int s[256];
  int i = blockIdx.x * 256 + threadIdx.x;
  int v = (i < N) ? deg[i] : 0;
  s[threadIdx.x] = v;
  __syncthreads();
#pragma unroll
  for (int off = 1; off < 256; off <<= 1) {
    int t = (threadIdx.x >= off) ? s[threadIdx.x - off] : 0;
    __syncthreads();
    s[threadIdx.x] += t;
    __syncthreads();
  }
  if (i < N) rp[i] = s[threadIdx.x] - v;
  if (threadIdx.x == 255) bsum[blockIdx.x] = s[255];
}

__global__ __launch_bounds__(512) void k_scan2(
    const int* __restrict__ bsum, int* __restrict__ bexcl, int B) {
  __shared__ int s[512];
  int v = (threadIdx.x < B) ? bsum[threadIdx.x] : 0;
  s[threadIdx.x] = v;
  __syncthreads();
#pragma unroll
  for (int off = 1; off < 512; off <<= 1) {
    int t = (threadIdx.x >= off) ? s[threadIdx.x - off] : 0;
    __syncthreads();
    s[threadIdx.x] += t;
    __syncthreads();
  }
  if (threadIdx.x < B) bexcl[threadIdx.x] = s[threadIdx.x] - v;
}

__global__ __launch_bounds__(256) void k_scan3(
    int* __restrict__ rp, const int* __restrict__ bexcl,
    int* __restrict__ cur, int N, int E) {
  int i = blockIdx.x * 256 + threadIdx.x;
  if (i < N) {
    int v = rp[i] + bexcl[blockIdx.x];
    rp[i] = v;
    cur[i] = v;
  }
  if (i == 0) rp[N] = E;
}

__global__ __launch_bounds__(256) void k_fill(
    const int* __restrict__ src, const int* __restrict__ dst,
    const int* __restrict__ et, const int* __restrict__ ed,
    int* __restrict__ cur, u32* __restrict__ adj, int E) {
  int e = blockIdx.x * 256 + threadIdx.x;
  if (e >= E) return;
  int pos = atomicAdd(&cur[dst[e]], 1);
  adj[pos] = (u32)src[e] | ((u32)et[e] << 17) | ((u32)ed[e] << 20);
}

// ---------- gather-aggregate (round-11 proven version) ----------
__global__ __launch_bounds__(256) void k_gather(
    const u16* __restrict__ h, const int* __restrict__ rp,
    const u32* __restrict__ adj, const float* __restrict__ ee1,
    const float* __restrict__ ee2, u16* __restrict__ aggb, int N) {
  int node = blockIdx.x * 4 + (threadIdx.x >> 6);
  if (node >= N) return;
  int lane = threadIdx.x & 63;
  int c = lane * 4;
  float4 a0 = b2f4(*(const ushort4v*)&h[(size_t)node * 256 + c]);
  float4 a1 = make_float4(0.f, 0.f, 0.f, 0.f);
  float4 a2 = a1, a3 = a1;
  u32 tcA = 0, tcB = 0;
  int beg = rp[node], end = rp[node + 1];
  int i = beg;
  for (; i + 4 <= end; i += 4) {
    u32 p0 = adj[i], p1 = adj[i + 1], p2 = adj[i + 2], p3 = adj[i + 3];
    float4 v0 = b2f4(*(const ushort4v*)&h[(size_t)(p0 & 0x1FFFF) * 256 + c]);
    float4 v1 = b2f4(*(const ushort4v*)&h[(size_t)(p1 & 0x1FFFF) * 256 + c]);
    float4 v2 = b2f4(*(const ushort4v*)&h[(size_t)(p2 & 0x1FFFF) * 256 + c]);
    float4 v3 = b2f4(*(const ushort4v*)&h[(size_t)(p3 & 0x1FFFF) * 256 + c]);
    a0.x += v0.x; a0.y += v0.y; a0.z += v0.z; a0.w += v0.w;
    a1.x += v1.x; a1.y += v1.y; a1.z += v1.z; a1.w += v1.w;
    a2.x += v2.x; a2.y += v2.y; a2.z += v2.z; a2.w += v2.w;
    a3.x += v3.x; a3.y += v3.y; a3.z += v3.z; a3.w += v3.w;
#pragma unroll
    for (int u = 0; u < 4; ++u) {
      u32 p = (u == 0) ? p0 : (u == 1) ? p1 : (u == 2) ? p2 : p3;
      u32 t = (p >> 17) & 7, r = (p >> 20) & 3;
      tcA += (t < 4) ? (1u << (t * 8)) : 0u;
      tcB += ((t == 4) ? 1u : 0u) + ((r == 0) ? 256u : 0u) +
             ((r == 1) ? 65536u : 0u);
    }
  }
  for (; i < end; ++i) {
    u32 p = adj[i];
    float4 v = b2f4(*(const ushort4v*)&h[(size_t)(p & 0x1FFFF) * 256 + c]);
    a0.x += v.x; a0.y += v.y; a0.z += v.z; a0.w += v.w;
    u32 t = (p >> 17) & 7, r = (p >> 20) & 3;
    tcA += (t < 4) ? (1u << (t * 8)) : 0u;
    tcB += ((t == 4) ? 1u : 0u) + ((r == 0) ? 256u : 0u) +
           ((r == 1) ? 65536u : 0u);
  }
  int deg = end - beg;
  int i0 = tcA & 255, i1 = (tcA >> 8) & 255, i2 = (tcA >> 16) & 255,
      i3 = (tcA >> 24) & 255;
  int i4 = (int)(tcB & 255) + 1;
  int r0 = (int)((tcB >> 8) & 255) + 1;
  int r1 = (int)((tcB >> 16) & 255);
  int i5 = deg - i0 - i1 - i2 - i3 - (i4 - 1);
  int r2 = deg - (r0 - 1) - r1;
  float ct[6], cr[3];
  ct[0] = (float)i0; ct[1] = (float)i1; ct[2] = (float)i2;
  ct[3] = (float)i3; ct[4] = (float)i4; ct[5] = (float)i5;
  cr[0] = (float)r0; cr[1] = (float)r1; cr[2] = (float)r2;

  float ax = a0.x + a1.x + a2.x + a3.x;
  float ay = a0.y + a1.y + a2.y + a3.y;
  float az = a0.z + a1.z + a2.z + a3.z;
  float aw = a0.w + a1.w + a2.w + a3.w;
#pragma unroll
  for (int t = 0; t < 6; ++t) {
    float4 e = *(const float4*)&ee1[t * 256 + c];
    ax += ct[t] * e.x; ay += ct[t] * e.y;
    az += ct[t] * e.z; aw += ct[t] * e.w;
  }
#pragma unroll
  for (int r = 0; r < 3; ++r) {
    float4 e = *(const float4*)&ee2[r * 256 + c];
    ax += cr[r] * e.x; ay += cr[r] * e.y;
    az += cr[r] * e.z; aw += cr[r] * e.w;
  }
  ushort4v o;
  o[0] = f2bf(ax); o[1] = f2bf(ay); o[2] = f2bf(az); o[3] = f2bf(aw);
  *(ushort4v*)&aggb[(size_t)node * 256 + c] = o;
}

// ---------- MFMA GEMM: 128x256 tile, 8 waves, BK=32, dbuf + counted vmcnt,
// conflict-free XOR-swizzled LDS (involution on 16B chunks:
// p = l ^ ((l>>3)&7)), setprio around MFMA, fused bias (+relu/bf16)
// + optional BN-stats.  OUTMODE: 0 = f32, 2 = bf16+relu.
template <int K, int NC, int OUTMODE, bool STATS>
__global__ __launch_bounds__(512) void k_gemm(
    const u16* __restrict__ A, const u16* __restrict__ Bt,
    const float* __restrict__ bias, void* __restrict__ outp,
    float* __restrict__ st, int M) {
  constexpr int NSTEP = K / 32;
  __shared__ u16 As[2][128 * 32];
  __shared__ u16 Bs[2][256 * 32];
  const int tid = threadIdx.x;
  const int lane = tid & 63;
  const int wv = tid >> 6;               // 0..7
  const int wrow = wv >> 2, wcol = wv & 3;
  const int m0 = blockIdx.x * 128;
  const int n0 = blockIdx.y * 256;
  const int fr = lane & 15;
  const int kg = lane >> 4;

  f32x4 acc[4][4];
#pragma unroll
  for (int m = 0; m < 4; ++m)
#pragma unroll
    for (int n = 0; n < 4; ++n) acc[m][n] = (f32x4){0.f, 0.f, 0.f, 0.f};

  // staging: physical chunk cidx holds logical chunk lidx = cidx^((cidx>>3)&7)
  auto stage = [&](int k0, int b) {
    {
      const int cidx = tid;
      const int lidx = cidx ^ ((cidx >> 3) & 7);
      int row = lidx >> 2, kcol = lidx & 3;
      int ar = m0 + row;
      if (ar >= M) ar = M - 1;
      gload_lds16(A + (size_t)ar * K + k0 + kcol * 8,
                  (char*)As[b] + (tid & ~63) * 16);
    }
#pragma unroll
    for (int j = 0; j < 2; ++j) {
      const int cidx = j * 512 + tid;
      const int lidx = cidx ^ ((cidx >> 3) & 7);
      int row = lidx >> 2, kcol = lidx & 3;
      gload_lds16(Bt + (size_t)(n0 + row) * K + k0 + kcol * 8,
                  (char*)Bs[b] + (j * 512 + (tid & ~63)) * 16);
    }
  };

  stage(0, 0);
  for (int ks = 0; ks < NSTEP; ++ks) {
    const int b = ks & 1;
    if (ks + 1 < NSTEP) {
      stage((ks + 1) * 32, b ^ 1);
      asm volatile("s_waitcnt vmcnt(3)" ::: "memory");
    } else {
      asm volatile("s_waitcnt vmcnt(0)" ::: "memory");
    }
    __builtin_amdgcn_sched_barrier(0);
    __builtin_amdgcn_s_barrier();
    __builtin_amdgcn_sched_barrier(0);
    bf16x8 af[4], bf[4];
#pragma unroll
    for (int m = 0; m < 4; ++m) {
      int row = wrow * 64 + m * 16 + fr;
      int off = ((row << 2) + kg) ^ ((row >> 1) & 7);
      af[m] = *(const bf16x8*)((const char*)As[b] + (off << 4));
    }
#pragma unroll
    for (int n = 0; n < 4; ++n) {
      int row = wcol * 64 + n * 16 + fr;
      int off = ((row << 2) + kg) ^ ((row >> 1) & 7);
      bf[n] = *(const bf16x8*)((const char*)Bs[b] + (off << 4));
    }
    __builtin_amdgcn_s_setprio(1);
#pragma unroll
    for (int m = 0; m < 4; ++m)
#pragma unroll
      for (int n = 0; n < 4; ++n)
        acc[m][n] = __builtin_amdgcn_mfma_f32_16x16x32_bf16(af[m], bf[n],
                                                            acc[m][n], 0, 0, 0);
    __builtin_amdgcn_s_setprio(0);
    __builtin_amdgcn_sched_barrier(0);
    __builtin_amdgcn_s_barrier();
  }

  float* sst = (float*)As;  // 512 floats: [0..255]=sum, [256..511]=sumsq
  if (STATS) {
    __syncthreads();
    sst[tid] = 0.f;
    __syncthreads();
  }

  const int rb = kg * 4;
  float s[4], s2[4];
#pragma unroll
  for (int n = 0; n < 4; ++n) { s[n] = 0.f; s2[n] = 0.f; }
#pragma unroll
  for (int m = 0; m < 4; ++m) {
#pragma unroll
    for (int n = 0; n < 4; ++n) {
      const int col = n0 + wcol * 64 + n * 16 + fr;
      const float bv = bias[col];
#pragma unroll
      for (int j = 0; j < 4; ++j) {
        const int row = m0 + wrow * 64 + m * 16 + rb + j;
        if (row < M) {
          float v = acc[m][n][j] + bv;
          if (OUTMODE == 2) {
            v = fmaxf(v, 0.f);
            ((u16*)outp)[(size_t)row * NC + col] = f2bf(v);
          } else {
            ((float*)outp)[(size_t)row * NC + col] = v;
          }
          if (STATS) {
            s[n] += v;
            s2[n] += v * v;
          }
        }
      }
    }
  }
  if (STATS) {
#pragma unroll
    for (int n = 0; n < 4; ++n) {
      s[n] += __shfl_xor(s[n], 16);
      s[n] += __shfl_xor(s[n], 32);
      s2[n] += __shfl_xor(s2[n], 16);
      s2[n] += __shfl_xor(s2[n], 32);
    }
    if (lane < 16) {
#pragma unroll
      for (int n = 0; n < 4; ++n) {
        const int col = wcol * 64 + n * 16 + fr;  // n0 == 0 when STATS
        atomicAdd(&sst[col], s[n]);
        atomicAdd(&sst[256 + col], s2[n]);
      }
    }
    __syncthreads();
    unsafeAtomicAdd(&st[tid], sst[tid]);
  }
}

// ---------- BN apply with inline finalize (reads raw sum/sumsq) ----------
// BF16RELU=true: relu + bf16 (next layer's h). false: f32 (final output).
template <bool BF16RELU>
__global__ __launch_bounds__(256) void k_bn_apply(
    const float* __restrict__ hl, const float* __restrict__ stats,
    const float* __restrict__ gamma, const float* __restrict__ beta,
    int l, float invN, void* __restrict__ out, int N) {
  int idx = blockIdx.x * 256 + threadIdx.x;
  if (idx >= N * 64) return;
  int c = (idx & 63) * 4;
  float4 sum = *(const float4*)&stats[c];
  float4 ssq = *(const float4*)&stats[256 + c];
  float4 g = *(const float4*)&gamma[l * 256 + c];
  float4 bt = *(const float4*)&beta[l * 256 + c];
  float4 mean = make_float4(sum.x * invN, sum.y * invN, sum.z * invN,
                            sum.w * invN);
  float4 sc, sh;
  sc.x = g.x * rsqrtf(ssq.x * invN - mean.x * mean.x + 1e-5f);
  sc.y = g.y * rsqrtf(ssq.y * invN - mean.y * mean.y + 1e-5f);
  sc.z = g.z * rsqrtf(ssq.z * invN - mean.z * mean.z + 1e-5f);
  sc.w = g.w * rsqrtf(ssq.w * invN - mean.w * mean.w + 1e-5f);
  sh.x = bt.x - mean.x * sc.x; sh.y = bt.y - mean.y * sc.y;
  sh.z = bt.z - mean.z * sc.z; sh.w = bt.w - mean.w * sc.w;
  float4 v = *(const float4*)&hl[(size_t)idx * 4];
  float4 o = make_float4(v.x * sc.x + sh.x, v.y * sc.y + sh.y,
                         v.z * sc.z + sh.z, v.w * sc.w + sh.w);
  if (BF16RELU) {
    ushort4v ob;
    ob[0] = f2bf(fmaxf(o.x, 0.f)); ob[1] = f2bf(fmaxf(o.y, 0.f));
    ob[2] = f2bf(fmaxf(o.z, 0.f)); ob[3] = f2bf(fmaxf(o.w, 0.f));
    *(ushort4v*)&((u16*)out)[(size_t)idx * 4] = ob;
  } else {
    *(float4*)&((float*)out)[(size_t)idx * 4] = o;
  }
}

// ---------- launch ----------
extern "C" void kernel_launch(void* const* d_in, const int* in_sizes, int n_in,
                              void* d_out, int out_size, void* d_ws,
                              size_t ws_size, hipStream_t stream) {
  const int* x_atom = (const int*)d_in[0];
  const int* x_chir = (const int*)d_in[1];
  const int* esrc = (const int*)d_in[2];
  const int* edst = (const int*)d_in[3];
  const int* etype = (const int*)d_in[4];
  const int* edir = (const int*)d_in[5];
  const float* x_emb1 = (const float*)d_in[6];
  const float* x_emb2 = (const float*)d_in[7];
  const float* eemb1 = (const float*)d_in[8];
  const float* eemb2 = (const float*)d_in[9];
  const float* W1 = (const float*)d_in[10];
  const float* b1 = (const float*)d_in[11];
  const float* W2 = (const float*)d_in[12];
  const float* b2 = (const float*)d_in[13];
  const float* gamma = (const float*)d_in[14];
  const float* beta = (const float*)d_in[15];

  const int N = in_sizes[0];
  const int E = in_sizes[2];

  char* ws = (char*)d_ws;
  size_t off = 0;
  char* bufA = ws + off; off += (size_t)N * 1024;  // hn (bf16) / interb
  char* bufB = ws + off; off += (size_t)N * 1024;  // hl (f32)
  u16* aggb = (u16*)(ws + off); off += (size_t)N * 256 * 2;
  u16* w1t = (u16*)(ws + off); off += (size_t)5 * 512 * 256 * 2;
  u16* w2t = (u16*)(ws + off); off += (size_t)5 * 256 * 512 * 2;
  int* rp = (int*)(ws + off); off += (size_t)(N + 1) * 4;
  int* degcur = (int*)(ws + off); off += (size_t)N * 4;
  int* bsum = (int*)(ws + off); off += 512 * 4;
  int* bexcl = (int*)(ws + off); off += 512 * 4;
  u32* adj = (u32*)(ws + off); off += (size_t)E * 4;
  float* statsAll = (float*)(ws + off); off += 5 * 1024 * 4;  // per-layer

  const int gN64 = (N * 64 + 255) / 256;
  const int gE = (E + 255) / 256;
  const int B1 = (N + 255) / 256;
  const int NB128 = (N + 127) / 128;  // 782

  u16* hn = (u16*)bufA;        // normalized bf16 h (input of each layer)
  u16* interb = (u16*)bufA;    // GEMM1 out, aliases hn (dead after gather)
  float* hl = (float*)bufB;    // raw GEMM2 out (f32)

  // --- one-time: CSR build + weight cast + node embed + stats zero ---
  hipMemsetAsync(degcur, 0, (size_t)N * 4, stream);
  hipMemsetAsync(statsAll, 0, 5 * 1024 * 4, stream);
  k_deg_count<<<gE, 256, 0, stream>>>(edst, degcur, E);
  k_scan1<<<B1, 256, 0, stream>>>(degcur, rp, bsum, N);
  k_scan2<<<1, 512, 0, stream>>>(bsum, bexcl, B1);
  k_scan3<<<B1, 256, 0, stream>>>(rp, bexcl, degcur, N, E);
  k_fill<<<gE, 256, 0, stream>>>(esrc, edst, etype, edir, degcur, adj, E);
  k_cast_weights<<<(2 * 5 * 512 * 256 + 255) / 256, 256, 0, stream>>>(W1, W2,
                                                                      w1t, w2t);
  k_node_init<<<gN64, 256, 0, stream>>>(x_atom, x_chir, x_emb1, x_emb2, hn, N);

  for (int l = 0; l < 5; ++l) {
    const float* ee1 = eemb1 + (size_t)l * 6 * 256;
    const float* ee2 = eemb2 + (size_t)l * 3 * 256;
    float* st = statsAll + l * 1024;

    k_gather<<<(N + 3) / 4, 256, 0, stream>>>(hn, rp, adj, ee1, ee2, aggb, N);
    k_gemm<256, 512, 2, false><<<dim3(NB128, 2), 512, 0, stream>>>(
        aggb, w1t + (size_t)l * 512 * 256, b1 + l * 512, interb, nullptr, N);
    k_gemm<512, 256, 0, true><<<dim3(NB128, 1), 512, 0, stream>>>(
        interb, w2t + (size_t)l * 256 * 512, b2 + l * 256, hl, st, N);
    if (l < 4)
      k_bn_apply<true><<<gN64, 256, 0, stream>>>(hl, st, gamma, beta, l,
                                                 1.f / N, hn, N);
    else
      k_bn_apply<false><<<gN64, 256, 0, stream>>>(hl, st, gamma, beta, l,
                                                  1.f / N, d_out, N);
  }
}

// Round 14
// 1249.766 us; speedup vs baseline: 1.1147x; 1.1147x over previous
//
#include <hip/hip_runtime.h>
#include <cstdint>

typedef float f32x4 __attribute__((ext_vector_type(4)));
typedef __bf16 bf16x8 __attribute__((ext_vector_type(8)));
typedef unsigned short ushort4v __attribute__((ext_vector_type(4)));
typedef unsigned short u16;
typedef unsigned int u32;

// ---------- helpers ----------
__device__ __forceinline__ u16 f2bf(float f) {
  u32 u = __builtin_bit_cast(u32, f);
  u32 r = (u + 0x7fffu + ((u >> 16) & 1u)) >> 16;
  return (u16)r;
}

__device__ __forceinline__ float4 b2f4(ushort4v v) {
  float4 o;
  o.x = __builtin_bit_cast(float, (u32)v[0] << 16);
  o.y = __builtin_bit_cast(float, (u32)v[1] << 16);
  o.z = __builtin_bit_cast(float, (u32)v[2] << 16);
  o.w = __builtin_bit_cast(float, (u32)v[3] << 16);
  return o;
}

__device__ __forceinline__ void gload_lds16(const void* g, void* lds) {
  __builtin_amdgcn_global_load_lds(
      (const __attribute__((address_space(1))) u32*)g,
      (__attribute__((address_space(3))) u32*)lds,
      16, 0, 0);
}

// ---------- one-time: cast + transpose weights to bf16 ----------
__global__ __launch_bounds__(256) void k_cast_weights(
    const float* __restrict__ W1, const float* __restrict__ W2,
    u16* __restrict__ w1t, u16* __restrict__ w2t) {
  const int PER = 5 * 512 * 256;
  int idx = blockIdx.x * 256 + threadIdx.x;
  if (idx < PER) {
    int l = idx / (512 * 256);
    int rem = idx % (512 * 256);
    int n = rem / 256, k = rem % 256;
    w1t[idx] = f2bf(W1[l * 131072 + k * 512 + n]);
  } else if (idx < 2 * PER) {
    int j = idx - PER;
    int l = j / (256 * 512);
    int rem = j % (256 * 512);
    int n = rem / 512, k = rem % 512;
    w2t[j] = f2bf(W2[l * 131072 + k * 256 + n]);
  }
}

// ---------- node input embedding (bf16 h0) ----------
__global__ __launch_bounds__(256) void k_node_init(
    const int* __restrict__ xa, const int* __restrict__ xc,
    const float* __restrict__ e1, const float* __restrict__ e2,
    u16* __restrict__ h, int N) {
  int idx = blockIdx.x * 256 + threadIdx.x;
  if (idx >= N * 64) return;
  int node = idx >> 6, c = (idx & 63) * 4;
  int a = xa[node], ch = xc[node];
  float4 v1 = *(const float4*)&e1[a * 256 + c];
  float4 v2 = *(const float4*)&e2[ch * 256 + c];
  ushort4v o;
  o[0] = f2bf(v1.x + v2.x); o[1] = f2bf(v1.y + v2.y);
  o[2] = f2bf(v1.z + v2.z); o[3] = f2bf(v1.w + v2.w);
  *(ushort4v*)&h[(size_t)node * 256 + c] = o;
}

// ---------- CSR build ----------
__global__ __launch_bounds__(256) void k_deg_count(
    const int* __restrict__ dst, int* __restrict__ deg, int E) {
  int e = blockIdx.x * 256 + threadIdx.x;
  if (e < E) atomicAdd(&deg[dst[e]], 1);
}

__global__ __launch_bounds__(256) void k_scan1(
    const int* __restrict__ deg, int* __restrict__ rp,
    int* __restrict__ bsum, int N) {
  __shared__ int s[256];
  int i = blockIdx.x * 256 + threadIdx.x;
  int v = (i < N) ? deg[i] : 0;
  s[threadIdx.x] = v;
  __syncthreads();
#pragma unroll
  for (int off = 1; off < 256; off <<= 1) {
    int t = (threadIdx.x >= off) ? s[threadIdx.x - off] : 0;
    __syncthreads();
    s[threadIdx.x] += t;
    __syncthreads();
  }
  if (i < N) rp[i] = s[threadIdx.x] - v;
  if (threadIdx.x == 255) bsum[blockIdx.x] = s[255];
}

__global__ __launch_bounds__(512) void k_scan2(
    const int* __restrict__ bsum, int* __restrict__ bexcl, int B) {
  __shared__ int s[512];
  int v = (threadIdx.x < B) ? bsum[threadIdx.x] : 0;
  s[threadIdx.x] = v;
  __syncthreads();
#pragma unroll
  for (int off = 1; off < 512; off <<= 1) {
    int t = (threadIdx.x >= off) ? s[threadIdx.x - off] : 0;
    __syncthreads();
    s[threadIdx.x] += t;
    __syncthreads();
  }
  if (threadIdx.x < B) bexcl[threadIdx.x] = s[threadIdx.x] - v;
}

__global__ __launch_bounds__(256) void k_scan3(
    int* __restrict__ rp, const int* __restrict__ bexcl,
    int* __restrict__ cur, int N, int E) {
  int i = blockIdx.x * 256 + threadIdx.x;
  if (i < N) {
    int v = rp[i] + bexcl[blockIdx.x];
    rp[i] = v;
    cur[i] = v;
  }
  if (i == 0) rp[N] = E;
}

__global__ __launch_bounds__(256) void k_fill(
    const int* __restrict__ src, const int* __restrict__ dst,
    const int* __restrict__ et, const int* __restrict__ ed,
    int* __restrict__ cur, u32* __restrict__ adj, int E) {
  int e = blockIdx.x * 256 + threadIdx.x;
  if (e >= E) return;
  int pos = atomicAdd(&cur[dst[e]], 1);
  adj[pos] = (u32)src[e] | ((u32)et[e] << 17) | ((u32)ed[e] << 20);
}

// ---------- gather-aggregate (round-11 proven version) ----------
__global__ __launch_bounds__(256) void k_gather(
    const u16* __restrict__ h, const int* __restrict__ rp,
    const u32* __restrict__ adj, const float* __restrict__ ee1,
    const float* __restrict__ ee2, u16* __restrict__ aggb, int N) {
  int node = blockIdx.x * 4 + (threadIdx.x >> 6);
  if (node >= N) return;
  int lane = threadIdx.x & 63;
  int c = lane * 4;
  float4 a0 = b2f4(*(const ushort4v*)&h[(size_t)node * 256 + c]);
  float4 a1 = make_float4(0.f, 0.f, 0.f, 0.f);
  float4 a2 = a1, a3 = a1;
  u32 tcA = 0, tcB = 0;
  int beg = rp[node], end = rp[node + 1];
  int i = beg;
  for (; i + 4 <= end; i += 4) {
    u32 p0 = adj[i], p1 = adj[i + 1], p2 = adj[i + 2], p3 = adj[i + 3];
    float4 v0 = b2f4(*(const ushort4v*)&h[(size_t)(p0 & 0x1FFFF) * 256 + c]);
    float4 v1 = b2f4(*(const ushort4v*)&h[(size_t)(p1 & 0x1FFFF) * 256 + c]);
    float4 v2 = b2f4(*(const ushort4v*)&h[(size_t)(p2 & 0x1FFFF) * 256 + c]);
    float4 v3 = b2f4(*(const ushort4v*)&h[(size_t)(p3 & 0x1FFFF) * 256 + c]);
    a0.x += v0.x; a0.y += v0.y; a0.z += v0.z; a0.w += v0.w;
    a1.x += v1.x; a1.y += v1.y; a1.z += v1.z; a1.w += v1.w;
    a2.x += v2.x; a2.y += v2.y; a2.z += v2.z; a2.w += v2.w;
    a3.x += v3.x; a3.y += v3.y; a3.z += v3.z; a3.w += v3.w;
#pragma unroll
    for (int u = 0; u < 4; ++u) {
      u32 p = (u == 0) ? p0 : (u == 1) ? p1 : (u == 2) ? p2 : p3;
      u32 t = (p >> 17) & 7, r = (p >> 20) & 3;
      tcA += (t < 4) ? (1u << (t * 8)) : 0u;
      tcB += ((t == 4) ? 1u : 0u) + ((r == 0) ? 256u : 0u) +
             ((r == 1) ? 65536u : 0u);
    }
  }
  for (; i < end; ++i) {
    u32 p = adj[i];
    float4 v = b2f4(*(const ushort4v*)&h[(size_t)(p & 0x1FFFF) * 256 + c]);
    a0.x += v.x; a0.y += v.y; a0.z += v.z; a0.w += v.w;
    u32 t = (p >> 17) & 7, r = (p >> 20) & 3;
    tcA += (t < 4) ? (1u << (t * 8)) : 0u;
    tcB += ((t == 4) ? 1u : 0u) + ((r == 0) ? 256u : 0u) +
           ((r == 1) ? 65536u : 0u);
  }
  int deg = end - beg;
  int i0 = tcA & 255, i1 = (tcA >> 8) & 255, i2 = (tcA >> 16) & 255,
      i3 = (tcA >> 24) & 255;
  int i4 = (int)(tcB & 255) + 1;
  int r0 = (int)((tcB >> 8) & 255) + 1;
  int r1 = (int)((tcB >> 16) & 255);
  int i5 = deg - i0 - i1 - i2 - i3 - (i4 - 1);
  int r2 = deg - (r0 - 1) - r1;
  float ct[6], cr[3];
  ct[0] = (float)i0; ct[1] = (float)i1; ct[2] = (float)i2;
  ct[3] = (float)i3; ct[4] = (float)i4; ct[5] = (float)i5;
  cr[0] = (float)r0; cr[1] = (float)r1; cr[2] = (float)r2;

  float ax = a0.x + a1.x + a2.x + a3.x;
  float ay = a0.y + a1.y + a2.y + a3.y;
  float az = a0.z + a1.z + a2.z + a3.z;
  float aw = a0.w + a1.w + a2.w + a3.w;
#pragma unroll
  for (int t = 0; t < 6; ++t) {
    float4 e = *(const float4*)&ee1[t * 256 + c];
    ax += ct[t] * e.x; ay += ct[t] * e.y;
    az += ct[t] * e.z; aw += ct[t] * e.w;
  }
#pragma unroll
  for (int r = 0; r < 3; ++r) {
    float4 e = *(const float4*)&ee2[r * 256 + c];
    ax += cr[r] * e.x; ay += cr[r] * e.y;
    az += cr[r] * e.z; aw += cr[r] * e.w;
  }
  ushort4v o;
  o[0] = f2bf(ax); o[1] = f2bf(ay); o[2] = f2bf(az); o[3] = f2bf(aw);
  *(ushort4v*)&aggb[(size_t)node * 256 + c] = o;
}

// ---------- MFMA GEMM: 128x256 tile, 8 waves, BK=32, dbuf + counted vmcnt,
// conflict-free XOR-swizzled LDS (involution on 16B chunks:
// p = l ^ ((l>>3)&7)), fused bias (+relu/bf16) + optional BN-stats.
// NO setprio (round-13 A/B: setprio cost ~40us/dispatch on this lockstep
// structure — matches m190).  OUTMODE: 0 = f32, 2 = bf16+relu.
template <int K, int NC, int OUTMODE, bool STATS>
__global__ __launch_bounds__(512) void k_gemm(
    const u16* __restrict__ A, const u16* __restrict__ Bt,
    const float* __restrict__ bias, void* __restrict__ outp,
    float* __restrict__ st, int M) {
  constexpr int NSTEP = K / 32;
  __shared__ u16 As[2][128 * 32];
  __shared__ u16 Bs[2][256 * 32];
  const int tid = threadIdx.x;
  const int lane = tid & 63;
  const int wv = tid >> 6;               // 0..7
  const int wrow = wv >> 2, wcol = wv & 3;
  const int m0 = blockIdx.x * 128;
  const int n0 = blockIdx.y * 256;
  const int fr = lane & 15;
  const int kg = lane >> 4;

  f32x4 acc[4][4];
#pragma unroll
  for (int m = 0; m < 4; ++m)
#pragma unroll
    for (int n = 0; n < 4; ++n) acc[m][n] = (f32x4){0.f, 0.f, 0.f, 0.f};

  // staging: physical chunk cidx holds logical chunk lidx = cidx^((cidx>>3)&7)
  auto stage = [&](int k0, int b) {
    {
      const int cidx = tid;
      const int lidx = cidx ^ ((cidx >> 3) & 7);
      int row = lidx >> 2, kcol = lidx & 3;
      int ar = m0 + row;
      if (ar >= M) ar = M - 1;
      gload_lds16(A + (size_t)ar * K + k0 + kcol * 8,
                  (char*)As[b] + (tid & ~63) * 16);
    }
#pragma unroll
    for (int j = 0; j < 2; ++j) {
      const int cidx = j * 512 + tid;
      const int lidx = cidx ^ ((cidx >> 3) & 7);
      int row = lidx >> 2, kcol = lidx & 3;
      gload_lds16(Bt + (size_t)(n0 + row) * K + k0 + kcol * 8,
                  (char*)Bs[b] + (j * 512 + (tid & ~63)) * 16);
    }
  };

  stage(0, 0);
  for (int ks = 0; ks < NSTEP; ++ks) {
    const int b = ks & 1;
    if (ks + 1 < NSTEP) {
      stage((ks + 1) * 32, b ^ 1);
      asm volatile("s_waitcnt vmcnt(3)" ::: "memory");
    } else {
      asm volatile("s_waitcnt vmcnt(0)" ::: "memory");
    }
    __builtin_amdgcn_sched_barrier(0);
    __builtin_amdgcn_s_barrier();
    __builtin_amdgcn_sched_barrier(0);
    bf16x8 af[4], bf[4];
#pragma unroll
    for (int m = 0; m < 4; ++m) {
      int row = wrow * 64 + m * 16 + fr;
      int off = ((row << 2) + kg) ^ ((row >> 1) & 7);
      af[m] = *(const bf16x8*)((const char*)As[b] + (off << 4));
    }
#pragma unroll
    for (int n = 0; n < 4; ++n) {
      int row = wcol * 64 + n * 16 + fr;
      int off = ((row << 2) + kg) ^ ((row >> 1) & 7);
      bf[n] = *(const bf16x8*)((const char*)Bs[b] + (off << 4));
    }
#pragma unroll
    for (int m = 0; m < 4; ++m)
#pragma unroll
      for (int n = 0; n < 4; ++n)
        acc[m][n] = __builtin_amdgcn_mfma_f32_16x16x32_bf16(af[m], bf[n],
                                                            acc[m][n], 0, 0, 0);
    __builtin_amdgcn_sched_barrier(0);
    __builtin_amdgcn_s_barrier();
  }

  float* sst = (float*)As;  // 512 floats: [0..255]=sum, [256..511]=sumsq
  if (STATS) {
    __syncthreads();
    sst[tid] = 0.f;
    __syncthreads();
  }

  const int rb = kg * 4;
  float s[4], s2[4];
#pragma unroll
  for (int n = 0; n < 4; ++n) { s[n] = 0.f; s2[n] = 0.f; }
#pragma unroll
  for (int m = 0; m < 4; ++m) {
#pragma unroll
    for (int n = 0; n < 4; ++n) {
      const int col = n0 + wcol * 64 + n * 16 + fr;
      const float bv = bias[col];
#pragma unroll
      for (int j = 0; j < 4; ++j) {
        const int row = m0 + wrow * 64 + m * 16 + rb + j;
        if (row < M) {
          float v = acc[m][n][j] + bv;
          if (OUTMODE == 2) {
            v = fmaxf(v, 0.f);
            ((u16*)outp)[(size_t)row * NC + col] = f2bf(v);
          } else {
            ((float*)outp)[(size_t)row * NC + col] = v;
          }
          if (STATS) {
            s[n] += v;
            s2[n] += v * v;
          }
        }
      }
    }
  }
  if (STATS) {
#pragma unroll
    for (int n = 0; n < 4; ++n) {
      s[n] += __shfl_xor(s[n], 16);
      s[n] += __shfl_xor(s[n], 32);
      s2[n] += __shfl_xor(s2[n], 16);
      s2[n] += __shfl_xor(s2[n], 32);
    }
    if (lane < 16) {
#pragma unroll
      for (int n = 0; n < 4; ++n) {
        const int col = wcol * 64 + n * 16 + fr;  // n0 == 0 when STATS
        atomicAdd(&sst[col], s[n]);
        atomicAdd(&sst[256 + col], s2[n]);
      }
    }
    __syncthreads();
    unsafeAtomicAdd(&st[tid], sst[tid]);
  }
}

// ---------- BN apply with inline finalize (reads raw sum/sumsq) ----------
// BF16RELU=true: relu + bf16 (next layer's h). false: f32 (final output).
template <bool BF16RELU>
__global__ __launch_bounds__(256) void k_bn_apply(
    const float* __restrict__ hl, const float* __restrict__ stats,
    const float* __restrict__ gamma, const float* __restrict__ beta,
    int l, float invN, void* __restrict__ out, int N) {
  int idx = blockIdx.x * 256 + threadIdx.x;
  if (idx >= N * 64) return;
  int c = (idx & 63) * 4;
  float4 sum = *(const float4*)&stats[c];
  float4 ssq = *(const float4*)&stats[256 + c];
  float4 g = *(const float4*)&gamma[l * 256 + c];
  float4 bt = *(const float4*)&beta[l * 256 + c];
  float4 mean = make_float4(sum.x * invN, sum.y * invN, sum.z * invN,
                            sum.w * invN);
  float4 sc, sh;
  sc.x = g.x * rsqrtf(ssq.x * invN - mean.x * mean.x + 1e-5f);
  sc.y = g.y * rsqrtf(ssq.y * invN - mean.y * mean.y + 1e-5f);
  sc.z = g.z * rsqrtf(ssq.z * invN - mean.z * mean.z + 1e-5f);
  sc.w = g.w * rsqrtf(ssq.w * invN - mean.w * mean.w + 1e-5f);
  sh.x = bt.x - mean.x * sc.x; sh.y = bt.y - mean.y * sc.y;
  sh.z = bt.z - mean.z * sc.z; sh.w = bt.w - mean.w * sc.w;
  float4 v = *(const float4*)&hl[(size_t)idx * 4];
  float4 o = make_float4(v.x * sc.x + sh.x, v.y * sc.y + sh.y,
                         v.z * sc.z + sh.z, v.w * sc.w + sh.w);
  if (BF16RELU) {
    ushort4v ob;
    ob[0] = f2bf(fmaxf(o.x, 0.f)); ob[1] = f2bf(fmaxf(o.y, 0.f));
    ob[2] = f2bf(fmaxf(o.z, 0.f)); ob[3] = f2bf(fmaxf(o.w, 0.f));
    *(ushort4v*)&((u16*)out)[(size_t)idx * 4] = ob;
  } else {
    *(float4*)&((float*)out)[(size_t)idx * 4] = o;
  }
}

// ---------- launch ----------
extern "C" void kernel_launch(void* const* d_in, const int* in_sizes, int n_in,
                              void* d_out, int out_size, void* d_ws,
                              size_t ws_size, hipStream_t stream) {
  const int* x_atom = (const int*)d_in[0];
  const int* x_chir = (const int*)d_in[1];
  const int* esrc = (const int*)d_in[2];
  const int* edst = (const int*)d_in[3];
  const int* etype = (const int*)d_in[4];
  const int* edir = (const int*)d_in[5];
  const float* x_emb1 = (const float*)d_in[6];
  const float* x_emb2 = (const float*)d_in[7];
  const float* eemb1 = (const float*)d_in[8];
  const float* eemb2 = (const float*)d_in[9];
  const float* W1 = (const float*)d_in[10];
  const float* b1 = (const float*)d_in[11];
  const float* W2 = (const float*)d_in[12];
  const float* b2 = (const float*)d_in[13];
  const float* gamma = (const float*)d_in[14];
  const float* beta = (const float*)d_in[15];

  const int N = in_sizes[0];
  const int E = in_sizes[2];

  char* ws = (char*)d_ws;
  size_t off = 0;
  char* bufA = ws + off; off += (size_t)N * 1024;  // hn (bf16) / interb
  char* bufB = ws + off; off += (size_t)N * 1024;  // hl (f32)
  u16* aggb = (u16*)(ws + off); off += (size_t)N * 256 * 2;
  u16* w1t = (u16*)(ws + off); off += (size_t)5 * 512 * 256 * 2;
  u16* w2t = (u16*)(ws + off); off += (size_t)5 * 256 * 512 * 2;
  int* rp = (int*)(ws + off); off += (size_t)(N + 1) * 4;
  int* degcur = (int*)(ws + off); off += (size_t)N * 4;
  int* bsum = (int*)(ws + off); off += 512 * 4;
  int* bexcl = (int*)(ws + off); off += 512 * 4;
  u32* adj = (u32*)(ws + off); off += (size_t)E * 4;
  float* statsAll = (float*)(ws + off); off += 5 * 1024 * 4;  // per-layer

  const int gN64 = (N * 64 + 255) / 256;
  const int gE = (E + 255) / 256;
  const int B1 = (N + 255) / 256;
  const int NB128 = (N + 127) / 128;  // 782

  u16* hn = (u16*)bufA;        // normalized bf16 h (input of each layer)
  u16* interb = (u16*)bufA;    // GEMM1 out, aliases hn (dead after gather)
  float* hl = (float*)bufB;    // raw GEMM2 out (f32)

  // --- one-time: CSR build + weight cast + node embed + stats zero ---
  hipMemsetAsync(degcur, 0, (size_t)N * 4, stream);
  hipMemsetAsync(statsAll, 0, 5 * 1024 * 4, stream);
  k_deg_count<<<gE, 256, 0, stream>>>(edst, degcur, E);
  k_scan1<<<B1, 256, 0, stream>>>(degcur, rp, bsum, N);
  k_scan2<<<1, 512, 0, stream>>>(bsum, bexcl, B1);
  k_scan3<<<B1, 256, 0, stream>>>(rp, bexcl, degcur, N, E);
  k_fill<<<gE, 256, 0, stream>>>(esrc, edst, etype, edir, degcur, adj, E);
  k_cast_weights<<<(2 * 5 * 512 * 256 + 255) / 256, 256, 0, stream>>>(W1, W2,
                                                                      w1t, w2t);
  k_node_init<<<gN64, 256, 0, stream>>>(x_atom, x_chir, x_emb1, x_emb2, hn, N);

  for (int l = 0; l < 5; ++l) {
    const float* ee1 = eemb1 + (size_t)l * 6 * 256;
    const float* ee2 = eemb2 + (size_t)l * 3 * 256;
    float* st = statsAll + l * 1024;

    k_gather<<<(N + 3) / 4, 256, 0, stream>>>(hn, rp, adj, ee1, ee2, aggb, N);
    k_gemm<256, 512, 2, false><<<dim3(NB128, 2), 512, 0, stream>>>(
        aggb, w1t + (size_t)l * 512 * 256, b1 + l * 512, interb, nullptr, N);
    k_gemm<512, 256, 0, true><<<dim3(NB128, 1), 512, 0, stream>>>(
        interb, w2t + (size_t)l * 256 * 512, b2 + l * 256, hl, st, N);
    if (l < 4)
      k_bn_apply<true><<<gN64, 256, 0, stream>>>(hl, st, gamma, beta, l,
                                                 1.f / N, hn, N);
    else
      k_bn_apply<false><<<gN64, 256, 0, stream>>>(hl, st, gamma, beta, l,
                                                  1.f / N, d_out, N);
  }
}